// Round 3
// baseline (87.891 us; speedup 1.0000x reference)
//
#include <hip/hip_runtime.h>
#include <hip/hip_fp16.h>

// ---- problem constants ----
#define B_    4096
#define F_    39
#define D_    16
#define NKK0  50           // layer0 K=32 chunks (40h * 5a * 8j / 32)
#define NKK1  80           // layer1 K=32 chunks (64h * 5a * 8j / 32)
#define NKK   130
#define NRND  65           // rounds of 2 kk
#define WP_HALFS (NKK * 4096)   // 532480 halfs = 1.04 MB

typedef _Float16 f16x8  __attribute__((ext_vector_type(8)));
typedef float    f32x4  __attribute__((ext_vector_type(4)));
typedef float    f32x16 __attribute__((ext_vector_type(16)));

union FragAB { f16x8 h8; __half2 h2[4]; f32x4 f4; __half h[8]; };

__device__ __forceinline__ void gload_lds16(const void* g, void* l) {
    __builtin_amdgcn_global_load_lds(
        (const __attribute__((address_space(1))) void*)g,
        (__attribute__((address_space(3))) void*)l, 16, 0, 0);
}

// ---------- W pre-pack into 32x32x16 A-fragment order, a-major K ----------
// Wp[kkg][Mt][ks][lane][j]; o = Mt*32 + (lane&31); k-local = 8*(lane>>5)+j
// u = 4*kkg_local + 2*ks + (lane>>5);  L0: a=u/40,h=u%40  L1: a=u>>6,h=u&63
__global__ __launch_bounds__(256) void prep_w(
    const float* __restrict__ W0, const float* __restrict__ W1,
    __half* __restrict__ Wp)
{
    int idx = blockIdx.x * 256 + threadIdx.x;
    if (idx >= WP_HALFS) return;
    int j   = idx & 7;
    int l   = (idx >> 3) & 63;
    int ks  = (idx >> 9) & 1;
    int Mt  = (idx >> 10) & 3;
    int kkg = idx >> 12;
    int o   = Mt * 32 + (l & 31);
    int sub = l >> 5;
    float v = 0.f;
    if (kkg < NKK0) {
        int u = 4 * kkg + 2 * ks + sub;            // < 200
        int a = u / 40, h = u - 40 * a, m = a * 8 + j;
        if (h < F_ && m < F_) v = W0[o * (F_ * F_) + h * F_ + m];
    } else {
        int u = 4 * (kkg - NKK0) + 2 * ks + sub;   // < 320
        int a = u >> 6, h = u & 63, m = a * 8 + j;
        if (m < F_) v = W1[o * (64 * F_) + h * F_ + m];
    }
    Wp[idx] = __float2half(v);
}

// ---------- one round = 2 kk (K=64), templated on layer & a-segment ----------
template<int LL, int AA>
__device__ __forceinline__ void do_round(
    int rr, int t, int sub,
    const __half* xrowA, const __half* xrowB,
    const __half* nrowA, const __half* nrowB,
    const FragAB (&xmc)[2][5], f32x16 (&acc)[2][2],
    __half* WlFlat, int wl_thread,
    int& buf, int& rg, const __half*& wsrc)
{
    // stage next round (counted: stays in flight across the compute below)
    if (rg < NRND - 1) {
        __half* dst = WlFlat + (buf ^ 1) * 8192;
#pragma unroll
        for (int it = 0; it < 4; ++it)
            gload_lds16(wsrc + it * 2048 + t * 8, dst + it * 2048 + t * 8);
        wsrc += 8192;
    }
    const __half* wl  = WlFlat + buf * 8192 + wl_thread;
    const __half* hbA = LL ? nrowA : xrowA;
    const __half* hbB = LL ? nrowB : xrowB;

#pragma unroll
    for (int kk2 = 0; kk2 < 2; ++kk2) {
#pragma unroll
        for (int ks = 0; ks < 2; ++ks) {
            const int hoff = 8 * rr + 4 * kk2 + 2 * ks + sub;
            __half2 xa2 = __half2half2(hbA[hoff]);
            __half2 xb2 = __half2half2(hbB[hoff]);
            FragAB bA, bB;
#pragma unroll
            for (int q = 0; q < 4; ++q) {
                bA.h2[q] = __hmul2(xmc[0][AA].h2[q], xa2);
                bB.h2[q] = __hmul2(xmc[1][AA].h2[q], xb2);
            }
#pragma unroll
            for (int mt = 0; mt < 2; ++mt) {
                FragAB A;
                A.f4 = *(const f32x4*)(wl + kk2 * 4096 + mt * 1024 + ks * 512);
                acc[mt][0] = __builtin_amdgcn_mfma_f32_32x32x16_f16(
                    A.h8, bA.h8, acc[mt][0], 0, 0, 0);
                acc[mt][1] = __builtin_amdgcn_mfma_f32_32x32x16_f16(
                    A.h8, bB.h8, acc[mt][1], 0, 0, 0);
            }
        }
    }
    asm volatile("s_waitcnt vmcnt(0)" ::: "memory");
    __syncthreads();
    buf ^= 1; ++rg;
}

// ---------- main: 512 blocks x 256 thr (4 waves); wave = 64 rows x 4 batches ----------
__global__ __launch_bounds__(256, 2) void cin_main(
    const float* __restrict__ x, const float* __restrict__ b0,
    const float* __restrict__ b1, const __half* __restrict__ Wp,
    float* __restrict__ out)
{
    __shared__ __align__(16) __half Wl[2][8192];      // 32 KB dbuf
    __shared__ __align__(16) __half xT[8][16][40];    // 10 KB  [bt][d][f]
    __shared__ __align__(16) __half nhT[8][16][68];   // 17 KB  [bt][d][h] (pad 68)

    const int t    = threadIdx.x;
    const int w    = t >> 6, lane = t & 63;
    const int sub  = lane >> 5, bp = (lane >> 4) & 1, d = lane & 15;
    const int g    = w >> 1, hi = w & 1;
    const int gb   = blockIdx.x * 8;

    // stage round 0 early (overlaps with xT fill)
#pragma unroll
    for (int it = 0; it < 4; ++it)
        gload_lds16(Wp + it * 2048 + t * 8, &Wl[0][0] + it * 2048 + t * 8);

    // xT fill: x[b][f][d] f32 -> xT[bt][d][f] fp16 (f=39 zero pad)
    for (int i = t; i < 8 * 156; i += 256) {
        int bt = i / 156, r2 = i - bt * 156;
        int f = r2 >> 2, dq = r2 & 3;
        const float4 v = *(const float4*)&x[((size_t)(gb + bt) * F_ + f) * D_ + dq * 4];
        xT[bt][dq * 4 + 0][f] = __float2half(v.x);
        xT[bt][dq * 4 + 1][f] = __float2half(v.y);
        xT[bt][dq * 4 + 2][f] = __float2half(v.z);
        xT[bt][dq * 4 + 3][f] = __float2half(v.w);
    }
    if (t < 128) xT[t >> 4][t & 15][39] = __float2half(0.f);

    asm volatile("s_waitcnt vmcnt(0)" ::: "memory");
    __syncthreads();

    // per-lane x row pointers + xm register cache (a = 0..4, compile-time)
    const int btA = g * 4 + bp;
    const int btB = g * 4 + 2 + bp;
    const __half* xrowA = &xT[btA][d][0];
    const __half* xrowB = &xT[btB][d][0];
    const __half* nrowA = &nhT[btA][d][0];
    const __half* nrowB = &nhT[btB][d][0];
    FragAB xmc[2][5];
#pragma unroll
    for (int a = 0; a < 5; ++a) {
        xmc[0][a].f4 = *(const f32x4*)(xrowA + a * 8);
        xmc[1][a].f4 = *(const f32x4*)(xrowB + a * 8);
    }

    // acc init = b0 (C/D row = (r&3)+8*(r>>2)+4*sub, col = lane&31)
    f32x16 acc[2][2];   // [mt][pair]
#pragma unroll
    for (int mt = 0; mt < 2; ++mt) {
        const int Mt = hi * 2 + mt;
#pragma unroll
        for (int r = 0; r < 16; ++r) {
            float bv = b0[Mt * 32 + (r & 3) + 8 * (r >> 2) + 4 * sub];
            acc[mt][0][r] = bv; acc[mt][1][r] = bv;
        }
    }

    const int wl_thread = (hi * 2) * 1024 + lane * 8;
    __half* WlFlat = &Wl[0][0];
    int buf = 0, rg = 0;
    const __half* wsrc = Wp + 8192;

    // ---- layer 0: 5 a-segments x 5 rounds ----
#pragma unroll 1
    for (int rr = 0; rr < 5; ++rr) do_round<0,0>(rr,t,sub,xrowA,xrowB,nrowA,nrowB,xmc,acc,WlFlat,wl_thread,buf,rg,wsrc);
#pragma unroll 1
    for (int rr = 0; rr < 5; ++rr) do_round<0,1>(rr,t,sub,xrowA,xrowB,nrowA,nrowB,xmc,acc,WlFlat,wl_thread,buf,rg,wsrc);
#pragma unroll 1
    for (int rr = 0; rr < 5; ++rr) do_round<0,2>(rr,t,sub,xrowA,xrowB,nrowA,nrowB,xmc,acc,WlFlat,wl_thread,buf,rg,wsrc);
#pragma unroll 1
    for (int rr = 0; rr < 5; ++rr) do_round<0,3>(rr,t,sub,xrowA,xrowB,nrowA,nrowB,xmc,acc,WlFlat,wl_thread,buf,rg,wsrc);
#pragma unroll 1
    for (int rr = 0; rr < 5; ++rr) do_round<0,4>(rr,t,sub,xrowA,xrowB,nrowA,nrowB,xmc,acc,WlFlat,wl_thread,buf,rg,wsrc);

    // ---- layer0 -> layer1 transition ----
    if (hi) {
        // rows 64..127 -> direct0 (out cols 0..63): reduce over d
#pragma unroll
        for (int mt = 0; mt < 2; ++mt) {
            const int Mt = 2 + mt;
#pragma unroll
            for (int p = 0; p < 2; ++p) {
#pragma unroll
                for (int r = 0; r < 16; ++r) {
                    float v = fmaxf(acc[mt][p][r], 0.f);
                    v += __shfl_xor(v, 1); v += __shfl_xor(v, 2);
                    v += __shfl_xor(v, 4); v += __shfl_xor(v, 8);
                    if (d == 0) {
                        int row = Mt * 32 + (r & 3) + 8 * (r >> 2) + 4 * sub;
                        int b   = gb + g * 4 + p * 2 + bp;
                        out[(size_t)b * 192 + (row - 64)] = v;
                    }
                }
            }
        }
    } else {
        // rows 0..63 -> nhT (fp16), packed 4-half writes
#pragma unroll
        for (int mt = 0; mt < 2; ++mt) {
#pragma unroll
            for (int p = 0; p < 2; ++p) {
                __half* nr = (__half*)(p ? nrowB : nrowA);
#pragma unroll
                for (int rg4 = 0; rg4 < 4; ++rg4) {
                    union { __half h[4]; float2 f2; } pk;
#pragma unroll
                    for (int q = 0; q < 4; ++q)
                        pk.h[q] = __float2half(fmaxf(acc[mt][p][rg4 * 4 + q], 0.f));
                    int row0 = mt * 32 + 8 * rg4 + 4 * sub;
                    *(float2*)(nr + row0) = pk.f2;
                }
            }
        }
    }
    // re-init acc = b1
#pragma unroll
    for (int mt = 0; mt < 2; ++mt) {
        const int Mt = hi * 2 + mt;
#pragma unroll
        for (int r = 0; r < 16; ++r) {
            float bv = b1[Mt * 32 + (r & 3) + 8 * (r >> 2) + 4 * sub];
            acc[mt][0][r] = bv; acc[mt][1][r] = bv;
        }
    }
    __syncthreads();   // nhT visible to all waves

    // ---- layer 1: 5 a-segments x 8 rounds ----
#pragma unroll 1
    for (int rr = 0; rr < 8; ++rr) do_round<1,0>(rr,t,sub,xrowA,xrowB,nrowA,nrowB,xmc,acc,WlFlat,wl_thread,buf,rg,wsrc);
#pragma unroll 1
    for (int rr = 0; rr < 8; ++rr) do_round<1,1>(rr,t,sub,xrowA,xrowB,nrowA,nrowB,xmc,acc,WlFlat,wl_thread,buf,rg,wsrc);
#pragma unroll 1
    for (int rr = 0; rr < 8; ++rr) do_round<1,2>(rr,t,sub,xrowA,xrowB,nrowA,nrowB,xmc,acc,WlFlat,wl_thread,buf,rg,wsrc);
#pragma unroll 1
    for (int rr = 0; rr < 8; ++rr) do_round<1,3>(rr,t,sub,xrowA,xrowB,nrowA,nrowB,xmc,acc,WlFlat,wl_thread,buf,rg,wsrc);
#pragma unroll 1
    for (int rr = 0; rr < 8; ++rr) do_round<1,4>(rr,t,sub,xrowA,xrowB,nrowA,nrowB,xmc,acc,WlFlat,wl_thread,buf,rg,wsrc);

    // ---- final epilogue: direct1 -> out cols 64..191 ----
#pragma unroll
    for (int mt = 0; mt < 2; ++mt) {
        const int Mt = hi * 2 + mt;
#pragma unroll
        for (int p = 0; p < 2; ++p) {
#pragma unroll
            for (int r = 0; r < 16; ++r) {
                float v = fmaxf(acc[mt][p][r], 0.f);
                v += __shfl_xor(v, 1); v += __shfl_xor(v, 2);
                v += __shfl_xor(v, 4); v += __shfl_xor(v, 8);
                if (d == 0) {
                    int row = Mt * 32 + (r & 3) + 8 * (r >> 2) + 4 * sub;
                    int b   = gb + g * 4 + p * 2 + bp;
                    out[(size_t)b * 192 + 64 + row] = v;
                }
            }
        }
    }
}

extern "C" void kernel_launch(void* const* d_in, const int* in_sizes, int n_in,
                              void* d_out, int out_size, void* d_ws, size_t ws_size,
                              hipStream_t stream) {
    const float* x  = (const float*)d_in[0];
    const float* W0 = (const float*)d_in[1];
    const float* b0 = (const float*)d_in[2];
    const float* W1 = (const float*)d_in[3];
    const float* b1 = (const float*)d_in[4];
    float* out = (float*)d_out;
    __half* Wp = (__half*)d_ws;   // 1.04 MB packed fragment-order weights

    prep_w<<<(WP_HALFS + 255) / 256, 256, 0, stream>>>(W0, W1, Wp);
    cin_main<<<B_ / 8, 256, 0, stream>>>(x, b0, b1, Wp, out);
}